// Round 11
// baseline (1995.696 us; speedup 1.0000x reference)
//
#include <hip/hip_runtime.h>

#define TT 512
#define BB 256
#define II 128
#define HH 256
#define LDH 264  // shorts/LDS row: 512B data + 16B pad (keeps 16B row alignment)

typedef __attribute__((ext_vector_type(8))) short short8;
typedef __attribute__((ext_vector_type(4))) float floatx4;
typedef __attribute__((ext_vector_type(4))) float fvec4;
typedef unsigned long long u64;

// ws layout (shorts): bf16 weights, h1g[2][B][H], h2g[2][B][H], then flags.
#define OFF_WIH0 0
#define OFF_WHH0 (OFF_WIH0 + 3 * HH * II)
#define OFF_WIH1 (OFF_WHH0 + 3 * HH * HH)
#define OFF_WHH1 (OFF_WIH1 + 3 * HH * HH)
#define W_TOTAL (OFF_WHH1 + 3 * HH * HH)
#define H1G_OFF W_TOTAL
#define H2G_OFF (H1G_OFF + 2 * BB * HH)
#define WS_SHORTS (H2G_OFF + 2 * BB * HH)
#define FLAGS_OFF_BYTES (WS_SHORTS * 2)
#define FLAG_STRIDE 32  // uints per bt-group; 8 flags live in one 64B line

__device__ __forceinline__ short f2bf(float f) {
  unsigned u = __builtin_bit_cast(unsigned, f);
  u = u + 0x7fffu + ((u >> 16) & 1u);
  return (short)(u >> 16);
}
__device__ __forceinline__ float fast_sigmoid(float x) {
  return __fdividef(1.0f, 1.0f + __expf(-x));
}
__device__ __forceinline__ float fast_tanh(float x) {
  return 1.0f - __fdividef(2.0f, 1.0f + __expf(2.0f * x));
}
__device__ __forceinline__ short8 cvt8(const float* __restrict__ p) {
  fvec4 lo = *(const fvec4*)p;
  fvec4 hi = *(const fvec4*)(p + 4);
  short8 r;
  r[0] = f2bf(lo[0]); r[1] = f2bf(lo[1]); r[2] = f2bf(lo[2]); r[3] = f2bf(lo[3]);
  r[4] = f2bf(hi[0]); r[5] = f2bf(hi[1]); r[6] = f2bf(hi[2]); r[7] = f2bf(hi[3]);
  return r;
}
__device__ __forceinline__ u64 ld_sc1(const u64* p) {
  return __hip_atomic_load(p, __ATOMIC_RELAXED, __HIP_MEMORY_SCOPE_AGENT);
}
__device__ __forceinline__ unsigned ld_flag(const unsigned* p) {
  return __hip_atomic_load(p, __ATOMIC_RELAXED, __HIP_MEMORY_SCOPE_AGENT);
}
__device__ __forceinline__ void st_flag(unsigned* p, unsigned v) {
  __hip_atomic_store(p, v, __ATOMIC_RELAXED, __HIP_MEMORY_SCOPE_AGENT);
}

__global__ __launch_bounds__(256) void cvt_weights(
    const float* __restrict__ w0, const float* __restrict__ w1,
    const float* __restrict__ w2, const float* __restrict__ w3,
    short* __restrict__ out) {
  int i = blockIdx.x * 256 + threadIdx.x;
  if (i >= W_TOTAL) return;
  float v;
  if (i < OFF_WHH0)      v = w0[i - OFF_WIH0];
  else if (i < OFF_WIH1) v = w1[i - OFF_WHH0];
  else if (i < OFF_WHH1) v = w2[i - OFF_WIH1];
  else                   v = w3[i - OFF_WHH1];
  out[i] = f2bf(v);
}

__global__ __launch_bounds__(256) void init_state(unsigned* __restrict__ hz,
                                                  unsigned* __restrict__ flags) {
  int i = blockIdx.x * 256 + threadIdx.x;
  if (i < 2 * BB * HH) hz[i] = 0u;  // h1g+h2g = 4*B*H shorts = 2*B*H uints
  if (i < 16 * FLAG_STRIDE) flags[i] = 0u;
}

// 128 blocks = (sub 0..7) x (bt 0..15), bid = sub*16 + bt -> XCD = bt%8:
// all 8 blocks of a bt-group co-locate on one XCD (R9-proven mapping).
// 384 thr = 6 waves; wave w: layer=w/3, gate=w%3; owns cols
// [sub*32, sub*32+32) = TWO 16-col MFMA tiles (vs R3's one). Group sync
// domain is 8 blocks instead of 16: per-step all-of-N detect waits on half
// the publishers -> straggler max-term and flag-line contention halve.
// Protocol is R3's verified one byte-for-byte: poll 64B flag line -> barrier
// -> reg-staged LDS staging -> barrier -> MFMA -> gt -> barrier -> elementwise
// + dword publish -> barrier (compiler drains) -> per-block flag store.
__global__ __launch_bounds__(384) void gru_sync(
    const float* __restrict__ x, const short* __restrict__ wb,
    const float* __restrict__ bih0, const float* __restrict__ bhh0,
    const float* __restrict__ bih1, const float* __restrict__ bhh1,
    const float* __restrict__ Wfc, const float* __restrict__ bfc,
    short* __restrict__ h1g, short* __restrict__ h2g,
    unsigned* __restrict__ flags, float* __restrict__ out) {
  const int tid = threadIdx.x;
  const int lane = tid & 63;
  const int w = tid >> 6;
  const int quad = lane >> 4;
  const int col = lane & 15;
  const int bt = blockIdx.x & 15;   // XCD = bt%8
  const int sub = blockIdx.x >> 4;  // 0..7: cols [sub*32, sub*32+32)
  const int layer = w / 3, gate = w % 3;
  const int j0 = sub * 32 + col;    // tile-0 output col
  const int j1 = j0 + 16;           // tile-1 output col

  __shared__ __align__(16) short ldsA[2][16][LDH];  // [0]=h1[p-1], [1]=h2[p-2]
  __shared__ __align__(16) float gt[2][6][16][36];  // 32 cols + 4 pad

  // ---- weights -> VGPRs: both col-tiles (wave-uniform role) ----
  const short* wih = wb + (layer ? OFF_WIH1 : OFF_WIH0);
  const short* whh = wb + (layer ? OFF_WHH1 : OFF_WHH0);
  const int KI = layer ? HH : II;
  short8 wfI0[8], wfI1[8], wfH0[8], wfH1[8];
#pragma unroll
  for (int f = 0; f < 8; ++f) {
    if (f * 32 < KI) {
      wfI0[f] = *(const short8*)(wih + (gate * HH + j0) * KI + f * 32 + quad * 8);
      wfI1[f] = *(const short8*)(wih + (gate * HH + j1) * KI + f * 32 + quad * 8);
    } else {
      wfI0[f] = short8{0, 0, 0, 0, 0, 0, 0, 0};
      wfI1[f] = short8{0, 0, 0, 0, 0, 0, 0, 0};
    }
    wfH0[f] = *(const short8*)(whh + (gate * HH + j0) * HH + f * 32 + quad * 8);
    wfH1[f] = *(const short8*)(whh + (gate * HH + j1) * HH + f * 32 + quad * 8);
  }
  const float* bihL = layer ? bih1 : bih0;
  const float* bhhL = layer ? bhh1 : bhh0;
  float bI_0, bH_0, bI_1, bH_1;
  if (gate == 2) {
    bI_0 = bihL[2 * HH + j0]; bH_0 = bhhL[2 * HH + j0];
    bI_1 = bihL[2 * HH + j1]; bH_1 = bhhL[2 * HH + j1];
  } else {
    bI_0 = bihL[gate * HH + j0] + bhhL[gate * HH + j0]; bH_0 = 0.f;
    bI_1 = bihL[gate * HH + j1] + bhhL[gate * HH + j1]; bH_1 = 0.f;
  }

  // ---- elementwise roles: (row, 2 cols) per thread over 16x32 ----
  float h1a = 0.f, h1b = 0.f, h2a = 0.f, h2b = 0.f;
  const int r1 = tid >> 4, c1 = (tid & 15) * 2;                // tid < 256
  const int r2 = (tid - 128) >> 4, c2 = ((tid - 128) & 15) * 2;  // tid >= 128

  unsigned* fl = flags + bt * FLAG_STRIDE;  // 8 slots, one 64B line
  const size_t tbase = (size_t)(bt * 16) * HH;

  for (int p = 0; p <= TT; ++p) {
    // x prefetch (L0 waves; A-frags shared by both col-tiles)
    short8 ax[4];
    if (w < 3 && p < TT) {
      const float* xr = x + ((size_t)p * BB + bt * 16 + col) * II + quad * 8;
#pragma unroll
      for (int f = 0; f < 4; ++f) ax[f] = cvt8(xr + f * 32);
    }

    if (p > 0) {
      if (w == 3) {  // dedicated poller wave (no x loads outstanding)
        const unsigned tgt = (unsigned)p;
        int guard = 0;
        for (;;) {
          unsigned v = (lane < 8) ? ld_flag(fl + lane) : tgt;
          if (__all(v >= tgt) || ++guard > (1 << 20)) break;
        }
      }
      __syncthreads();
    }

    // ---- stage peer tiles: loads -> regs (one wait), then LDS (R3 code) ----
    {
      const u64* s1 = (const u64*)(h1g + ((p + 1) & 1) * BB * HH + tbase);
      const u64* s2 = (const u64*)(h2g + (p & 1) * BB * HH + tbase);
      u64 t1[4], t2[4];
      if (tid < 256) {
#pragma unroll
        for (int qq = 0; qq < 4; ++qq) t1[qq] = ld_sc1(s1 + tid * 4 + qq);
      }
      if (tid >= 128) {
        const int ti = tid - 128;
#pragma unroll
        for (int qq = 0; qq < 4; ++qq) t2[qq] = ld_sc1(s2 + ti * 4 + qq);
      }
      u64* d1 = (u64*)&ldsA[0][0][0];
      u64* d2 = (u64*)&ldsA[1][0][0];
      if (tid < 256) {
#pragma unroll
        for (int qq = 0; qq < 4; ++qq) {
          int i = tid * 4 + qq, row = i >> 6, c = i & 63;
          d1[row * (LDH / 4) + c] = t1[qq];
        }
      }
      if (tid >= 128) {
        const int ti = tid - 128;
#pragma unroll
        for (int qq = 0; qq < 4; ++qq) {
          int i = ti * 4 + qq, row = i >> 6, c = i & 63;
          d2[row * (LDH / 4) + c] = t2[qq];
        }
      }
    }
    __syncthreads();

    // ---- MFMA: two col-tiles per wave (A-frags shared) ----
    floatx4 aI0 = floatx4{bI_0, bI_0, bI_0, bI_0};
    floatx4 aH0 = floatx4{bH_0, bH_0, bH_0, bH_0};
    floatx4 aI1 = floatx4{bI_1, bI_1, bI_1, bI_1};
    floatx4 aH1 = floatx4{bH_1, bH_1, bH_1, bH_1};
    const short* a1 = &ldsA[0][col][0];
    const short* a2 = &ldsA[1][col][0];
    if (layer == 0) {
      if (p < TT) {
#pragma unroll
        for (int f = 0; f < 4; ++f) {
          aI0 = __builtin_amdgcn_mfma_f32_16x16x32_bf16(ax[f], wfI0[f], aI0, 0, 0, 0);
          aI1 = __builtin_amdgcn_mfma_f32_16x16x32_bf16(ax[f], wfI1[f], aI1, 0, 0, 0);
        }
      }
#pragma unroll
      for (int f = 0; f < 8; ++f) {
        short8 a = *(const short8*)(a1 + f * 32 + quad * 8);
        aH0 = __builtin_amdgcn_mfma_f32_16x16x32_bf16(a, wfH0[f], aH0, 0, 0, 0);
        aH1 = __builtin_amdgcn_mfma_f32_16x16x32_bf16(a, wfH1[f], aH1, 0, 0, 0);
      }
    } else {
#pragma unroll
      for (int f = 0; f < 8; ++f) {
        short8 a = *(const short8*)(a1 + f * 32 + quad * 8);
        aI0 = __builtin_amdgcn_mfma_f32_16x16x32_bf16(a, wfI0[f], aI0, 0, 0, 0);
        aI1 = __builtin_amdgcn_mfma_f32_16x16x32_bf16(a, wfI1[f], aI1, 0, 0, 0);
      }
#pragma unroll
      for (int f = 0; f < 8; ++f) {
        short8 a = *(const short8*)(a2 + f * 32 + quad * 8);
        aH0 = __builtin_amdgcn_mfma_f32_16x16x32_bf16(a, wfH0[f], aH0, 0, 0, 0);
        aH1 = __builtin_amdgcn_mfma_f32_16x16x32_bf16(a, wfH1[f], aH1, 0, 0, 0);
      }
    }
#pragma unroll
    for (int i = 0; i < 4; ++i) {
      gt[0][w][quad * 4 + i][col] = aI0[i];
      gt[0][w][quad * 4 + i][col + 16] = aI1[i];
      gt[1][w][quad * 4 + i][col] = aH0[i];
      gt[1][w][quad * 4 + i][col + 16] = aH1[i];
    }
    __syncthreads();

    // ---- elementwise + dword publish (R3 pattern, 32 cols) ----
    if (tid < 256 && p < TT) {
      float rA = fast_sigmoid(gt[0][0][r1][c1] + gt[1][0][r1][c1]);
      float zA = fast_sigmoid(gt[0][1][r1][c1] + gt[1][1][r1][c1]);
      float nA = fast_tanh(gt[0][2][r1][c1] + rA * gt[1][2][r1][c1]);
      h1a = nA + zA * (h1a - nA);
      float rB = fast_sigmoid(gt[0][0][r1][c1 + 1] + gt[1][0][r1][c1 + 1]);
      float zB = fast_sigmoid(gt[0][1][r1][c1 + 1] + gt[1][1][r1][c1 + 1]);
      float nB = fast_tanh(gt[0][2][r1][c1 + 1] + rB * gt[1][2][r1][c1 + 1]);
      h1b = nB + zB * (h1b - nB);
      unsigned val = ((unsigned)(unsigned short)f2bf(h1b) << 16) |
                     (unsigned)(unsigned short)f2bf(h1a);
      unsigned* dst = (unsigned*)(h1g + (p & 1) * BB * HH +
                                  (bt * 16 + r1) * HH + sub * 32 + c1);
      __hip_atomic_store(dst, val, __ATOMIC_RELAXED, __HIP_MEMORY_SCOPE_AGENT);
    }
    if (tid >= 128 && p > 0) {
      float rA = fast_sigmoid(gt[0][3][r2][c2] + gt[1][3][r2][c2]);
      float zA = fast_sigmoid(gt[0][4][r2][c2] + gt[1][4][r2][c2]);
      float nA = fast_tanh(gt[0][5][r2][c2] + rA * gt[1][5][r2][c2]);
      h2a = nA + zA * (h2a - nA);
      float rB = fast_sigmoid(gt[0][3][r2][c2 + 1] + gt[1][3][r2][c2 + 1]);
      float zB = fast_sigmoid(gt[0][4][r2][c2 + 1] + gt[1][4][r2][c2 + 1]);
      float nB = fast_tanh(gt[0][5][r2][c2 + 1] + rB * gt[1][5][r2][c2 + 1]);
      h2b = nB + zB * (h2b - nB);
      unsigned val = ((unsigned)(unsigned short)f2bf(h2b) << 16) |
                     (unsigned)(unsigned short)f2bf(h2a);
      unsigned* dst = (unsigned*)(h2g + ((p + 1) & 1) * BB * HH +
                                  (bt * 16 + r2) * HH + sub * 32 + c2);
      __hip_atomic_store(dst, val, __ATOMIC_RELAXED, __HIP_MEMORY_SCOPE_AGENT);
    }
    __syncthreads();  // compiler-inserted vmcnt(0) drains all publishes
    if (tid == 0) st_flag(fl + sub, (unsigned)(p + 1));  // plain store, no RMW
  }

  // ---- FC epilogue: out = h2[TT-1] @ Wfc^T + bfc (two tiles, waves 0-1) ----
  if (w == 3) {
    const unsigned tgt = (unsigned)(TT + 1);
    int guard = 0;
    for (;;) {
      unsigned v = (lane < 8) ? ld_flag(fl + lane) : tgt;
      if (__all(v >= tgt) || ++guard > (1 << 20)) break;
    }
  }
  __syncthreads();
  {
    const u64* s1 = (const u64*)(h2g + 1 * BB * HH + tbase);  // parity (TT+1)&1=1
    u64 t1[4];
    if (tid < 256) {
#pragma unroll
      for (int qq = 0; qq < 4; ++qq) t1[qq] = ld_sc1(s1 + tid * 4 + qq);
    }
    u64* d1 = (u64*)&ldsA[0][0][0];
    if (tid < 256) {
#pragma unroll
      for (int qq = 0; qq < 4; ++qq) {
        int i = tid * 4 + qq, row = i >> 6, c = i & 63;
        d1[row * (LDH / 4) + c] = t1[qq];
      }
    }
  }
  __syncthreads();
  if (w < 2) {
    const int jf = sub * 32 + w * 16 + col;
    float bbv = bfc[jf];
    floatx4 acc = floatx4{bbv, bbv, bbv, bbv};
#pragma unroll
    for (int f = 0; f < 8; ++f) {
      short8 a = *(const short8*)(&ldsA[0][col][0] + f * 32 + quad * 8);
      short8 bfrag = cvt8(Wfc + jf * HH + f * 32 + quad * 8);
      acc = __builtin_amdgcn_mfma_f32_16x16x32_bf16(a, bfrag, acc, 0, 0, 0);
    }
#pragma unroll
    for (int i = 0; i < 4; ++i)
      out[(size_t)(bt * 16 + quad * 4 + i) * HH + jf] = acc[i];
  }
}

extern "C" void kernel_launch(void* const* d_in, const int* in_sizes, int n_in,
                              void* d_out, int out_size, void* d_ws,
                              size_t ws_size, hipStream_t stream) {
  const float* x = (const float*)d_in[0];
  const float* Wih0 = (const float*)d_in[1];
  const float* Whh0 = (const float*)d_in[2];
  const float* bih0 = (const float*)d_in[3];
  const float* bhh0 = (const float*)d_in[4];
  const float* Wih1 = (const float*)d_in[5];
  const float* Whh1 = (const float*)d_in[6];
  const float* bih1 = (const float*)d_in[7];
  const float* bhh1 = (const float*)d_in[8];
  const float* Wfc = (const float*)d_in[9];
  const float* bfc = (const float*)d_in[10];

  short* wb = (short*)d_ws;
  short* h1g = wb + H1G_OFF;
  short* h2g = wb + H2G_OFF;
  unsigned* flags = (unsigned*)((char*)d_ws + FLAGS_OFF_BYTES);
  unsigned* hz = (unsigned*)(wb + H1G_OFF);

  cvt_weights<<<(W_TOTAL + 255) / 256, 256, 0, stream>>>(Wih0, Whh0, Wih1, Whh1, wb);
  init_state<<<(2 * BB * HH + 255) / 256, 256, 0, stream>>>(hz, flags);
  gru_sync<<<128, 384, 0, stream>>>(x, wb, bih0, bhh0, bih1, bhh1, Wfc, bfc,
                                    h1g, h2g, flags, (float*)d_out);
}